// Round 3
// baseline (12579.311 us; speedup 1.0000x reference)
//
#include <hip/hip_runtime.h>
#include <stdint.h>

// Problem dims
#define BATCH 128
#define SEQ   512
#define DIN   256
#define HID   512
#define LDKA  776   // padded LDS K-stride (shorts), layer0 K=768
#define LDKB  1032  // layer1 K=1024
#define NWG_A 32
#define NWG   64
#define TPB   512   // 8 waves = (Mh 0..1) x (colt 0..3)
#define NSLOT 513
#define OUTD  1275

typedef __attribute__((ext_vector_type(8))) short bf16x8;
typedef __attribute__((ext_vector_type(8))) unsigned short ushort8;
typedef __attribute__((ext_vector_type(4))) float f32x4;

static __device__ __forceinline__ unsigned short f2bf(float f) {
  unsigned int u = __builtin_bit_cast(unsigned int, f);
  u += 0x7FFFu + ((u >> 16) & 1u);  // RNE
  return (unsigned short)(u >> 16);
}
static __device__ __forceinline__ float sigmoidf_fast(float v) {
  float e = __expf(-fabsf(v));
  float s = 1.0f / (1.0f + e);
  return v >= 0.0f ? s : 1.0f - s;
}
static __device__ __forceinline__ float tanhf_fast(float v) {
  float e = __expf(-2.0f * fabsf(v));
  float t = (1.0f - e) / (1.0f + e);
  return v >= 0.0f ? t : -t;
}

// x -> bf16 MFMA-fragment order: xb[(((p*8+mi)*8+kt)*64+lane)*8]
__global__ __launch_bounds__(256) void xprep(const float* __restrict__ x,
                                             unsigned short* __restrict__ xb) {
  int p = blockIdx.x;
  int lane = threadIdx.x & 63;
  int g4 = threadIdx.x >> 6;
  int c15 = lane & 15, q = lane >> 4;
  for (int g = 0; g < 16; ++g) {
    int idx = g * 4 + g4;  // (mi,kt)
    int mi = idx >> 3, kt = idx & 7;
    int row = mi * 16 + c15;
    const float* src = x + ((size_t)row * SEQ + p) * DIN + kt * 32 + q * 8;
    f32x4 a = *(const f32x4*)src;
    f32x4 b = *(const f32x4*)(src + 4);
    bf16x8 v;
    v[0] = (short)f2bf(a[0]); v[1] = (short)f2bf(a[1]);
    v[2] = (short)f2bf(a[2]); v[3] = (short)f2bf(a[3]);
    v[4] = (short)f2bf(b[0]); v[5] = (short)f2bf(b[1]);
    v[6] = (short)f2bf(b[2]); v[7] = (short)f2bf(b[3]);
    *(bf16x8*)&xb[((((size_t)p * 8 + mi) * 8 + kt) * 64 + lane) * 8] = v;
  }
}

// Gate epilogue. Wave = (Mh, colt=(Nh,tt)); tt=1 owns g/o, tt=0 owns i/f + cell.
static __device__ __forceinline__ void gate_epilogue(
    f32x4* acc, f32x4* cst, int tt, int s, int u, int Nh, int Mh, int q,
    float* exch, unsigned short* stage, bool writeFin, float* h1fin, int unit0)
{
  if (tt == 1) {
#pragma unroll
    for (int mi = 0; mi < 4; ++mi)
#pragma unroll
      for (int r = 0; r < 4; ++r) {
        float a = acc[mi][r];            // s==0: g-pre, s==1: o-pre
        float pr = __shfl_xor(a, 8);     // partner gate
        if (s == 0) {
          int row = Mh * 64 + mi * 16 + q * 4 + r;
          exch[row * 16 + Nh * 8 + u] = tanhf_fast(a);
          exch[2048 + row * 16 + Nh * 8 + u] = sigmoidf_fast(pr);
        }
      }
  }
  __syncthreads();
  if (tt == 0) {
#pragma unroll
    for (int mi = 0; mi < 4; ++mi)
#pragma unroll
      for (int r = 0; r < 4; ++r) {
        float a = acc[mi][r];            // s==0: i-pre, s==1: f-pre
        float pr = __shfl_xor(a, 8);
        if (s == 0) {
          int row = Mh * 64 + mi * 16 + q * 4 + r;
          float tg = exch[row * 16 + Nh * 8 + u];
          float so = exch[2048 + row * 16 + Nh * 8 + u];
          float cn = sigmoidf_fast(pr) * cst[mi][r] + sigmoidf_fast(a) * tg;
          cst[mi][r] = cn;
          float hn = so * tanhf_fast(cn);
          stage[row * 16 + Nh * 8 + u] = f2bf(hn);
          if (writeFin) h1fin[(size_t)row * HID + unit0 + Nh * 8 + u] = hn;
        }
      }
  }
}

// Persistent 2-layer LSTM, 64 WGs x 512 thr. Weights live in VGPRs (B-frags
// stationary per wave); LDS used once for weight transpose-staging, then
// reused as epilogue exchange + h-stage. One grid barrier per slot.
template <bool USE_XB>
__global__ __launch_bounds__(TPB) void lstm_persistent(
    const float* __restrict__ x, const unsigned short* __restrict__ xb,
    const float* __restrict__ W0, const float* __restrict__ b0,
    const float* __restrict__ W1, const float* __restrict__ b1,
    unsigned int* __restrict__ bar_cnt, unsigned short* __restrict__ h0buf,
    unsigned short* __restrict__ h1buf, float* __restrict__ h1fin)
{
  __shared__ unsigned short smem[64 * LDKB];  // 132 KB; dead after preload
  float* exch = (float*)smem;                  // 2 x 2048 f32 (16 KB)
  unsigned short* stage = &smem[8192];         // 128 x 16 bf16 (4 KB)

  const int tid  = threadIdx.x;
  const int wgid = blockIdx.x;
  const bool isA = (wgid < NWG_A);
  const int unit0 = (isA ? wgid : (wgid - NWG_A)) << 4;
  const int kt0   = unit0 >> 5;
  const int qbase = (unit0 >> 3) & 3;
  const int lane = tid & 63;
  const int wv   = tid >> 6;
  const int Mh   = wv & 1;        // batch half (4 M-tiles)
  const int ct   = wv >> 1;       // colt 0..3 = (Nh, tt)
  const int Nh   = ct >> 1;
  const int tt   = ct & 1;        // 0: i/f cols, 1: g/o cols
  const int c15  = lane & 15;
  const int q    = lane >> 4;
  const int s    = (lane >> 3) & 1;
  const int u    = lane & 7;

  // ---- stage weights -> LDS [col][k] bf16 (one-time) ----
  {
    const int K = isA ? 768 : 1024;
    const int ldk = isA ? LDKA : LDKB;
    const float* W = isA ? W0 : W1;
    for (int idx = tid; idx < 64 * K; idx += TPB) {
      int cc = idx & 63;
      int kk = idx >> 6;
      int gate = (((cc >> 4) & 1) << 1) | ((cc >> 3) & 1);
      int gcol = gate * HID + unit0 + (cc >> 5) * 8 + (cc & 7);
      smem[cc * ldk + kk] = f2bf(W[(size_t)kk * 2048 + gcol]);
    }
  }
  __syncthreads();

  const float* bv = isA ? b0 : b1;
  const float bias = bv[(tt * 2 + s) * HID + unit0 + Nh * 8 + u];

  f32x4 cst[4];  // cell state (tt==0, s==0 lanes): rows Mh*64+mi*16+q*4+r
#pragma unroll
  for (int mi = 0; mi < 4; ++mi) cst[mi] = (f32x4){0.f, 0.f, 0.f, 0.f};

  if (isA) {
    // ================= layer 0 =================
    bf16x8 B0[24];  // stationary weights: colt ct, kt 0..23 (96 VGPRs)
#pragma unroll
    for (int kt = 0; kt < 24; ++kt)
      B0[kt] = *(const bf16x8*)&smem[(ct * 16 + c15) * LDKA + kt * 32 + q * 8];
    __syncthreads();  // weights consumed; LDS reused below

    for (int p = 0; p < NSLOT; ++p) {
      const unsigned short* h0rd = h0buf + ((p + 1) & 1) * (BATCH * HID);
      unsigned short* h0wr       = h0buf + (p & 1) * (BATCH * HID);
      const bool active = (p < SEQ);

      f32x4 acc[4];
#pragma unroll
      for (int mi = 0; mi < 4; ++mi) acc[mi] = (f32x4){bias, bias, bias, bias};

      if (active) {  // x-part: no barrier dependency
#pragma unroll
        for (int mi = 0; mi < 4; ++mi) {
          int miG = Mh * 4 + mi;
          bf16x8 ax[8];
          if (USE_XB) {
            const unsigned short* xp = xb + ((((size_t)p * 8 + miG) * 8) * 64 + lane) * 8;
#pragma unroll
            for (int kt = 0; kt < 8; ++kt)
              ax[kt] = *(const bf16x8*)(xp + (size_t)kt * 64 * 8);
          } else {
            const float* xp0 = x + (((size_t)(miG * 16 + c15)) * SEQ + p) * DIN + q * 8;
#pragma unroll
            for (int kt = 0; kt < 8; ++kt) {
              f32x4 a = *(const f32x4*)(xp0 + kt * 32);
              f32x4 b = *(const f32x4*)(xp0 + kt * 32 + 4);
              ax[kt][0] = (short)f2bf(a[0]); ax[kt][1] = (short)f2bf(a[1]);
              ax[kt][2] = (short)f2bf(a[2]); ax[kt][3] = (short)f2bf(a[3]);
              ax[kt][4] = (short)f2bf(b[0]); ax[kt][5] = (short)f2bf(b[1]);
              ax[kt][6] = (short)f2bf(b[2]); ax[kt][7] = (short)f2bf(b[3]);
            }
          }
#pragma unroll
          for (int kt = 0; kt < 8; ++kt)
            acc[mi] = __builtin_amdgcn_mfma_f32_16x16x32_bf16(ax[kt], B0[kt], acc[mi], 0, 0, 0);
        }
      }

      // wait for slot p-1 publication
      __syncthreads();
      if (tid == 0 && p > 0) {
        unsigned int target = (unsigned int)p * NWG;
        while (__hip_atomic_load(bar_cnt, __ATOMIC_RELAXED, __HIP_MEMORY_SCOPE_AGENT) < target)
          __builtin_amdgcn_s_sleep(1);
        (void)__hip_atomic_load(bar_cnt, __ATOMIC_ACQUIRE, __HIP_MEMORY_SCOPE_AGENT);
      }
      __syncthreads();

      if (active) {
#pragma unroll
        for (int mi = 0; mi < 4; ++mi) {
          int miG = Mh * 4 + mi;
          const unsigned short* hp = h0rd + ((size_t)miG * 16 * 64) * 8 + (size_t)lane * 8;
#pragma unroll
          for (int half = 0; half < 2; ++half) {
            bf16x8 ah[8];
#pragma unroll
            for (int j = 0; j < 8; ++j)
              ah[j] = *(const bf16x8*)(hp + (size_t)(half * 8 + j) * 64 * 8);
#pragma unroll
            for (int j = 0; j < 8; ++j)
              acc[mi] = __builtin_amdgcn_mfma_f32_16x16x32_bf16(ah[j], B0[8 + half * 8 + j], acc[mi], 0, 0, 0);
          }
        }
        gate_epilogue(acc, cst, tt, s, u, Nh, Mh, q, exch, stage, false, h1fin, unit0);
      }
      __syncthreads();
      if (active && tid < 256) {
        int mi2 = tid >> 5, qq = (tid >> 4) & 1, r15 = tid & 15;
        ushort8 v = *(const ushort8*)&stage[(mi2 * 16 + r15) * 16 + qq * 8];
        unsigned short* dst = h0wr + (((size_t)mi2 * 16 + kt0) * 64 + (qbase + qq) * 16 + r15) * 8;
        __builtin_nontemporal_store(v, (ushort8*)dst);
      }
      __syncthreads();  // vmcnt drain before release
      if (tid == 0)
        __hip_atomic_fetch_add(bar_cnt, 1u, __ATOMIC_RELEASE, __HIP_MEMORY_SCOPE_AGENT);
    }
  } else {
    // ================= layer 1 =================
    bf16x8 B1[32];  // stationary weights: colt ct, kt 0..31 (128 VGPRs)
#pragma unroll
    for (int kt = 0; kt < 32; ++kt)
      B1[kt] = *(const bf16x8*)&smem[(ct * 16 + c15) * LDKB + kt * 32 + q * 8];
    __syncthreads();

    for (int p = 0; p < NSLOT; ++p) {
      const unsigned short* h0rd = h0buf + ((p + 1) & 1) * (BATCH * HID);
      const unsigned short* h1rd = h1buf + (p & 1) * (BATCH * HID);
      unsigned short* h1wr       = h1buf + ((p + 1) & 1) * (BATCH * HID);
      const bool active = (p >= 1);

      f32x4 acc[4];
#pragma unroll
      for (int mi = 0; mi < 4; ++mi) acc[mi] = (f32x4){bias, bias, bias, bias};

      __syncthreads();
      if (tid == 0 && p > 0) {
        unsigned int target = (unsigned int)p * NWG;
        while (__hip_atomic_load(bar_cnt, __ATOMIC_RELAXED, __HIP_MEMORY_SCOPE_AGENT) < target)
          __builtin_amdgcn_s_sleep(1);
        (void)__hip_atomic_load(bar_cnt, __ATOMIC_ACQUIRE, __HIP_MEMORY_SCOPE_AGENT);
      }
      __syncthreads();

      if (active) {
#pragma unroll
        for (int mi = 0; mi < 4; ++mi) {
          int miG = Mh * 4 + mi;
          const unsigned short* hp0 = h0rd + ((size_t)miG * 16 * 64) * 8 + (size_t)lane * 8;
          const unsigned short* hp1 = h1rd + ((size_t)miG * 16 * 64) * 8 + (size_t)lane * 8;
#pragma unroll
          for (int half = 0; half < 2; ++half) {
            bf16x8 a0[8];
#pragma unroll
            for (int j = 0; j < 8; ++j)
              a0[j] = *(const bf16x8*)(hp0 + (size_t)(half * 8 + j) * 64 * 8);
#pragma unroll
            for (int j = 0; j < 8; ++j)
              acc[mi] = __builtin_amdgcn_mfma_f32_16x16x32_bf16(a0[j], B1[half * 8 + j], acc[mi], 0, 0, 0);
          }
#pragma unroll
          for (int half = 0; half < 2; ++half) {
            bf16x8 a1[8];
#pragma unroll
            for (int j = 0; j < 8; ++j)
              a1[j] = *(const bf16x8*)(hp1 + (size_t)(half * 8 + j) * 64 * 8);
#pragma unroll
            for (int j = 0; j < 8; ++j)
              acc[mi] = __builtin_amdgcn_mfma_f32_16x16x32_bf16(a1[j], B1[16 + half * 8 + j], acc[mi], 0, 0, 0);
          }
        }
        gate_epilogue(acc, cst, tt, s, u, Nh, Mh, q, exch, stage, p == NSLOT - 1, h1fin, unit0);
      }
      __syncthreads();
      if (active && tid < 256) {
        int mi2 = tid >> 5, qq = (tid >> 4) & 1, r15 = tid & 15;
        ushort8 v = *(const ushort8*)&stage[(mi2 * 16 + r15) * 16 + qq * 8];
        unsigned short* dst = h1wr + (((size_t)mi2 * 16 + kt0) * 64 + (qbase + qq) * 16 + r15) * 8;
        __builtin_nontemporal_store(v, (ushort8*)dst);
      }
      __syncthreads();
      if (tid == 0)
        __hip_atomic_fetch_add(bar_cnt, 1u, __ATOMIC_RELEASE, __HIP_MEMORY_SCOPE_AGENT);
    }
  }
}

__global__ __launch_bounds__(256) void proj_kernel(
    const float* __restrict__ h1, const float* __restrict__ Wp,
    const float* __restrict__ bp, float* __restrict__ out)
{
  int o = blockIdx.x * 256 + threadIdx.x;
  int b = blockIdx.y;
  if (o >= OUTD) return;
  const float* hr = h1 + (size_t)b * HID;
  float acc = bp[o];
#pragma unroll 8
  for (int k = 0; k < HID; ++k)
    acc = fmaf(hr[k], Wp[(size_t)k * OUTD + o], acc);
  out[(size_t)b * OUTD + o] = acc;
}

extern "C" void kernel_launch(void* const* d_in, const int* in_sizes, int n_in,
                              void* d_out, int out_size, void* d_ws, size_t ws_size,
                              hipStream_t stream) {
  const float* x  = (const float*)d_in[0];
  const float* W0 = (const float*)d_in[1];
  const float* b0 = (const float*)d_in[2];
  const float* W1 = (const float*)d_in[3];
  const float* b1 = (const float*)d_in[4];
  const float* Wp = (const float*)d_in[5];
  const float* bp = (const float*)d_in[6];
  float* out = (float*)d_out;

  char* ws = (char*)d_ws;
  unsigned int* cnt   = (unsigned int*)ws;                        // 4 KB
  unsigned short* h0b = (unsigned short*)(ws + 4096);             // 256 KB (2 slots)
  unsigned short* h1b = (unsigned short*)(ws + 4096 + 262144);    // 256 KB
  float* h1fin        = (float*)(ws + 4096 + 2 * 262144);         // 256 KB
  unsigned short* xbp = (unsigned short*)(ws + 4096 + 3 * 262144);// 32 MB
  const size_t need_xb = 4096 + 3 * 262144 + (size_t)SEQ * BATCH * DIN * 2;
  const bool use_xb = (ws_size >= need_xb);

  hipMemsetAsync(d_ws, 0, 4096 + 2 * 262144, stream);
  if (use_xb) {
    hipLaunchKernelGGL(xprep, dim3(SEQ), dim3(256), 0, stream, x, xbp);
    hipLaunchKernelGGL(lstm_persistent<true>, dim3(NWG), dim3(TPB), 0, stream,
                       x, xbp, W0, b0, W1, b1, cnt, h0b, h1b, h1fin);
  } else {
    hipLaunchKernelGGL(lstm_persistent<false>, dim3(NWG), dim3(TPB), 0, stream,
                       x, xbp, W0, b0, W1, b1, cnt, h0b, h1b, h1fin);
  }
  hipLaunchKernelGGL(proj_kernel, dim3((OUTD + 255) / 256, BATCH), dim3(256), 0, stream,
                     h1fin, Wp, bp, out);
}

// Round 4
// 9921.230 us; speedup vs baseline: 1.2679x; 1.2679x over previous
//
#include <hip/hip_runtime.h>
#include <stdint.h>

// Problem dims
#define BATCH 128
#define SEQ   512
#define DIN   256
#define HID   512
#define LDKA  776    // padded LDS K-stride (shorts) for one-time weight staging, layer0
#define LDKB  1032   // layer1
#define NWG_L0 128
#define NWG   256    // 1 WG per CU
#define TPB   256    // 4 waves = 1 wave/SIMD -> 512-VGPR budget
#define NSLOT 513
#define OUTD  1275
#define HSLOT (BATCH * HID)

typedef __attribute__((ext_vector_type(8))) short bf16x8;
typedef __attribute__((ext_vector_type(4))) unsigned short ushort4v;
typedef __attribute__((ext_vector_type(4))) float f32x4;

static __device__ __forceinline__ unsigned short f2bf(float f) {
  unsigned int u = __builtin_bit_cast(unsigned int, f);
  u += 0x7FFFu + ((u >> 16) & 1u);  // RNE
  return (unsigned short)(u >> 16);
}
static __device__ __forceinline__ float sigmoidf_fast(float v) {
  float e = __expf(-fabsf(v));
  float s = 1.0f / (1.0f + e);
  return v >= 0.0f ? s : 1.0f - s;
}
static __device__ __forceinline__ float tanhf_fast(float v) {
  float e = __expf(-2.0f * fabsf(v));
  float t = (1.0f - e) / (1.0f + e);
  return v >= 0.0f ? t : -t;
}

// x -> bf16 MFMA-fragment order: xb[(((p*8+mi)*8+kt)*64+lane)*8]
__global__ __launch_bounds__(256) void xprep(const float* __restrict__ x,
                                             unsigned short* __restrict__ xb) {
  int p = blockIdx.x;
  int lane = threadIdx.x & 63;
  int g4 = threadIdx.x >> 6;
  int c15 = lane & 15, q = lane >> 4;
  for (int g = 0; g < 16; ++g) {
    int idx = g * 4 + g4;  // (mi,kt)
    int mi = idx >> 3, kt = idx & 7;
    int row = mi * 16 + c15;
    const float* src = x + ((size_t)row * SEQ + p) * DIN + kt * 32 + q * 8;
    f32x4 a = *(const f32x4*)src;
    f32x4 b = *(const f32x4*)(src + 4);
    bf16x8 v;
    v[0] = (short)f2bf(a[0]); v[1] = (short)f2bf(a[1]);
    v[2] = (short)f2bf(a[2]); v[3] = (short)f2bf(a[3]);
    v[4] = (short)f2bf(b[0]); v[5] = (short)f2bf(b[1]);
    v[6] = (short)f2bf(b[2]); v[7] = (short)f2bf(b[3]);
    *(bf16x8*)&xb[((((size_t)p * 8 + mi) * 8 + kt) * 64 + lane) * 8] = v;
  }
}

// Persistent 2-layer LSTM. 256 WGs x 256 thr (1/CU). WG owns 4 units of one
// layer; its 16 gate-cols (i,f,g,o x 4 units) = one MFMA col-tile whose
// B-fragments live in VGPRs (one-time LDS transpose-staging; 512-VGPR budget
// at 1 wave/SIMD). Wave = 32 batch rows. Cell state in VGPRs. Gate pairing via
// shfl_xor (all 4 gates in-wave). h exchanged in fragment layout via global
// scratch; one grid barrier per slot (relaxed poll + single acquire).
template <bool USE_XB>
__global__ __launch_bounds__(TPB, 1) void lstm_persistent(
    const float* __restrict__ x, const unsigned short* __restrict__ xb,
    const float* __restrict__ W0, const float* __restrict__ b0,
    const float* __restrict__ W1, const float* __restrict__ b1,
    unsigned int* __restrict__ bar_cnt, unsigned short* __restrict__ h0buf,
    unsigned short* __restrict__ h1buf, float* __restrict__ h1fin)
{
  __shared__ unsigned short sW[16 * LDKB];     // 33 KB, dead after preload
  __shared__ unsigned short stage[BATCH * 4];  // 128 rows x 4 units (1 KB)

  const int tid  = threadIdx.x;
  const int wgid = blockIdx.x;
  const bool isA = (wgid < NWG_L0);
  const int unit0 = (isA ? wgid : (wgid - NWG_L0)) << 2;  // 4 units per WG
  const int kt0 = unit0 >> 5;          // fragment indices of this unit block
  const int q0  = (unit0 >> 3) & 3;
  const int j0  = unit0 & 7;           // 0 or 4
  const int lane = tid & 63;
  const int wv   = tid >> 6;           // 0..3: rows [wv*32, wv*32+32)
  const int c15  = lane & 15;          // col: gate = c15>>2, unit = c15&3
  const int q    = lane >> 4;
  const int uu   = c15 & 3;
  const int gate = c15 >> 2;

  // ---- one-time: stage own 16 weight cols -> LDS [col][k], then to VGPRs ----
  {
    const int K = isA ? 768 : 1024;
    const int ldk = isA ? LDKA : LDKB;
    const float* W = isA ? W0 : W1;
    for (int idx = tid; idx < 16 * K; idx += TPB) {
      int cc = idx & 15;
      int kk = idx >> 4;
      int gcol = (cc >> 2) * HID + unit0 + (cc & 3);
      sW[cc * ldk + kk] = f2bf(W[(size_t)kk * 2048 + gcol]);
    }
  }
  __syncthreads();

  const float* bv = isA ? b0 : b1;
  const float bias = bv[gate * HID + unit0 + uu];

  f32x4 cst[2];  // cell state (c15<4 lanes): rows wv*32+sub*16+q*4+r, unit uu
  cst[0] = (f32x4){0.f, 0.f, 0.f, 0.f};
  cst[1] = (f32x4){0.f, 0.f, 0.f, 0.f};

  if (isA) {
    // ================= layer 0 (128 WGs) =================
    bf16x8 B0[24];  // stationary: 16 cols x K=768 (96 VGPRs)
#pragma unroll
    for (int kt = 0; kt < 24; ++kt)
      B0[kt] = *(const bf16x8*)&sW[c15 * LDKA + kt * 32 + q * 8];
    __syncthreads();

    for (int p = 0; p < NSLOT; ++p) {
      const unsigned short* h0rd = h0buf + ((p + 1) & 1) * HSLOT;
      unsigned short* h0wr       = h0buf + (p & 1) * HSLOT;
      const bool active = (p < SEQ);

      f32x4 acc[2];
      acc[0] = (f32x4){bias, bias, bias, bias};
      acc[1] = (f32x4){bias, bias, bias, bias};

      if (active) {  // x-part: no barrier dependency (overlaps the wait)
#pragma unroll
        for (int sub = 0; sub < 2; ++sub) {
          int miG = wv * 2 + sub;
          bf16x8 ax[8];
          if (USE_XB) {
            const unsigned short* xp = xb + ((((size_t)p * 8 + miG) * 8) * 64 + lane) * 8;
#pragma unroll
            for (int kt = 0; kt < 8; ++kt)
              ax[kt] = *(const bf16x8*)(xp + (size_t)kt * 64 * 8);
          } else {
            const float* xp0 = x + (((size_t)(miG * 16 + c15)) * SEQ + p) * DIN + q * 8;
#pragma unroll
            for (int kt = 0; kt < 8; ++kt) {
              f32x4 a = *(const f32x4*)(xp0 + kt * 32);
              f32x4 b = *(const f32x4*)(xp0 + kt * 32 + 4);
              ax[kt][0] = (short)f2bf(a[0]); ax[kt][1] = (short)f2bf(a[1]);
              ax[kt][2] = (short)f2bf(a[2]); ax[kt][3] = (short)f2bf(a[3]);
              ax[kt][4] = (short)f2bf(b[0]); ax[kt][5] = (short)f2bf(b[1]);
              ax[kt][6] = (short)f2bf(b[2]); ax[kt][7] = (short)f2bf(b[3]);
            }
          }
#pragma unroll
          for (int kt = 0; kt < 8; ++kt)
            acc[sub] = __builtin_amdgcn_mfma_f32_16x16x32_bf16(ax[kt], B0[kt], acc[sub], 0, 0, 0);
        }
      }

      __syncthreads();
      if (tid == 0 && p > 0) {
        unsigned int target = (unsigned int)p * NWG;
        while (__hip_atomic_load(bar_cnt, __ATOMIC_RELAXED, __HIP_MEMORY_SCOPE_AGENT) < target)
          __builtin_amdgcn_s_sleep(1);
        (void)__hip_atomic_load(bar_cnt, __ATOMIC_ACQUIRE, __HIP_MEMORY_SCOPE_AGENT);
      }
      __syncthreads();

      if (active) {
#pragma unroll
        for (int sub = 0; sub < 2; ++sub) {
          int miG = wv * 2 + sub;
          const unsigned short* hp = h0rd + ((size_t)miG * 16 * 64) * 8 + (size_t)lane * 8;
          bf16x8 ah[16];
#pragma unroll
          for (int j = 0; j < 16; ++j)
            ah[j] = *(const bf16x8*)(hp + (size_t)j * 64 * 8);
#pragma unroll
          for (int j = 0; j < 16; ++j)
            acc[sub] = __builtin_amdgcn_mfma_f32_16x16x32_bf16(ah[j], B0[8 + j], acc[sub], 0, 0, 0);
        }
        // gates: all 4 gates in-wave (i:0-3, f:4-7, g:8-11, o:12-15)
#pragma unroll
        for (int sub = 0; sub < 2; ++sub)
#pragma unroll
          for (int r = 0; r < 4; ++r) {
            float v = acc[sub][r];
            float vf = __shfl_xor(v, 4);
            float vg = __shfl_xor(v, 8);
            float vo = __shfl_xor(v, 12);
            if (c15 < 4) {
              float cn = sigmoidf_fast(vf) * cst[sub][r] + sigmoidf_fast(v) * tanhf_fast(vg);
              cst[sub][r] = cn;
              float hn = sigmoidf_fast(vo) * tanhf_fast(cn);
              int grow = wv * 32 + sub * 16 + q * 4 + r;
              stage[grow * 4 + uu] = f2bf(hn);
            }
          }
      }
      __syncthreads();
      if (active && tid < 128) {  // publish 4 units x 128 rows, fragment layout
        int mi = tid >> 4, r15 = tid & 15;
        ushort4v v = *(const ushort4v*)&stage[tid * 4];
        unsigned short* dst = h0wr + (((size_t)mi * 16 + kt0) * 64 + q0 * 16 + r15) * 8 + j0;
        __builtin_nontemporal_store(v, (ushort4v*)dst);
      }
      __syncthreads();  // vmcnt drain before release
      if (tid == 0)
        __hip_atomic_fetch_add(bar_cnt, 1u, __ATOMIC_RELEASE, __HIP_MEMORY_SCOPE_AGENT);
    }
  } else {
    // ================= layer 1 (128 WGs) =================
    bf16x8 B1[32];  // stationary: 16 cols x K=1024 (128 VGPRs)
#pragma unroll
    for (int kt = 0; kt < 32; ++kt)
      B1[kt] = *(const bf16x8*)&sW[c15 * LDKB + kt * 32 + q * 8];
    __syncthreads();

    for (int p = 0; p < NSLOT; ++p) {
      const unsigned short* h0rd = h0buf + ((p + 1) & 1) * HSLOT;
      const unsigned short* h1rd = h1buf + (p & 1) * HSLOT;
      unsigned short* h1wr       = h1buf + ((p + 1) & 1) * HSLOT;
      const bool active = (p >= 1);

      f32x4 acc[2];
      acc[0] = (f32x4){bias, bias, bias, bias};
      acc[1] = (f32x4){bias, bias, bias, bias};

      __syncthreads();
      if (tid == 0 && p > 0) {
        unsigned int target = (unsigned int)p * NWG;
        while (__hip_atomic_load(bar_cnt, __ATOMIC_RELAXED, __HIP_MEMORY_SCOPE_AGENT) < target)
          __builtin_amdgcn_s_sleep(1);
        (void)__hip_atomic_load(bar_cnt, __ATOMIC_ACQUIRE, __HIP_MEMORY_SCOPE_AGENT);
      }
      __syncthreads();

      if (active) {
#pragma unroll
        for (int sub = 0; sub < 2; ++sub) {
          int miG = wv * 2 + sub;
          const unsigned short* hp0 = h0rd + ((size_t)miG * 16 * 64) * 8 + (size_t)lane * 8;
          const unsigned short* hp1 = h1rd + ((size_t)miG * 16 * 64) * 8 + (size_t)lane * 8;
          bf16x8 a0[16], a1[16];
#pragma unroll
          for (int j = 0; j < 16; ++j)
            a0[j] = *(const bf16x8*)(hp0 + (size_t)j * 64 * 8);
#pragma unroll
          for (int j = 0; j < 16; ++j)
            a1[j] = *(const bf16x8*)(hp1 + (size_t)j * 64 * 8);
#pragma unroll
          for (int j = 0; j < 16; ++j)
            acc[sub] = __builtin_amdgcn_mfma_f32_16x16x32_bf16(a0[j], B1[j], acc[sub], 0, 0, 0);
#pragma unroll
          for (int j = 0; j < 16; ++j)
            acc[sub] = __builtin_amdgcn_mfma_f32_16x16x32_bf16(a1[j], B1[16 + j], acc[sub], 0, 0, 0);
        }
#pragma unroll
        for (int sub = 0; sub < 2; ++sub)
#pragma unroll
          for (int r = 0; r < 4; ++r) {
            float v = acc[sub][r];
            float vf = __shfl_xor(v, 4);
            float vg = __shfl_xor(v, 8);
            float vo = __shfl_xor(v, 12);
            if (c15 < 4) {
              float cn = sigmoidf_fast(vf) * cst[sub][r] + sigmoidf_fast(v) * tanhf_fast(vg);
              cst[sub][r] = cn;
              float hn = sigmoidf_fast(vo) * tanhf_fast(cn);
              int grow = wv * 32 + sub * 16 + q * 4 + r;
              stage[grow * 4 + uu] = f2bf(hn);
              if (p == NSLOT - 1)
                h1fin[(size_t)grow * HID + unit0 + uu] = hn;
            }
          }
      }
      __syncthreads();
      if (active && tid < 128) {
        int mi = tid >> 4, r15 = tid & 15;
        ushort4v v = *(const ushort4v*)&stage[tid * 4];
        unsigned short* dst = h1wr + (((size_t)mi * 16 + kt0) * 64 + q0 * 16 + r15) * 8 + j0;
        __builtin_nontemporal_store(v, (ushort4v*)dst);
      }
      __syncthreads();
      if (tid == 0)
        __hip_atomic_fetch_add(bar_cnt, 1u, __ATOMIC_RELEASE, __HIP_MEMORY_SCOPE_AGENT);
    }
  }
}

__global__ __launch_bounds__(256) void proj_kernel(
    const float* __restrict__ h1, const float* __restrict__ Wp,
    const float* __restrict__ bp, float* __restrict__ out)
{
  int o = blockIdx.x * 256 + threadIdx.x;
  int b = blockIdx.y;
  if (o >= OUTD) return;
  const float* hr = h1 + (size_t)b * HID;
  float acc = bp[o];
#pragma unroll 8
  for (int k = 0; k < HID; ++k)
    acc = fmaf(hr[k], Wp[(size_t)k * OUTD + o], acc);
  out[(size_t)b * OUTD + o] = acc;
}

extern "C" void kernel_launch(void* const* d_in, const int* in_sizes, int n_in,
                              void* d_out, int out_size, void* d_ws, size_t ws_size,
                              hipStream_t stream) {
  const float* x  = (const float*)d_in[0];
  const float* W0 = (const float*)d_in[1];
  const float* b0 = (const float*)d_in[2];
  const float* W1 = (const float*)d_in[3];
  const float* b1 = (const float*)d_in[4];
  const float* Wp = (const float*)d_in[5];
  const float* bp = (const float*)d_in[6];
  float* out = (float*)d_out;

  char* ws = (char*)d_ws;
  unsigned int* cnt   = (unsigned int*)ws;                        // 4 KB
  unsigned short* h0b = (unsigned short*)(ws + 4096);             // 256 KB (2 slots)
  unsigned short* h1b = (unsigned short*)(ws + 4096 + 262144);    // 256 KB
  float* h1fin        = (float*)(ws + 4096 + 2 * 262144);         // 256 KB
  unsigned short* xbp = (unsigned short*)(ws + 4096 + 3 * 262144);// 32 MB
  const size_t need_xb = 4096 + 3 * 262144 + (size_t)SEQ * BATCH * DIN * 2;
  const bool use_xb = (ws_size >= need_xb);

  hipMemsetAsync(d_ws, 0, 4096 + 2 * 262144, stream);
  if (use_xb) {
    hipLaunchKernelGGL(xprep, dim3(SEQ), dim3(256), 0, stream, x, xbp);
    hipLaunchKernelGGL(lstm_persistent<true>, dim3(NWG), dim3(TPB), 0, stream,
                       x, xbp, W0, b0, W1, b1, cnt, h0b, h1b, h1fin);
  } else {
    hipLaunchKernelGGL(lstm_persistent<false>, dim3(NWG), dim3(TPB), 0, stream,
                       x, xbp, W0, b0, W1, b1, cnt, h0b, h1b, h1fin);
  }
  hipLaunchKernelGGL(proj_kernel, dim3((OUTD + 255) / 256, BATCH), dim3(256), 0, stream,
                     h1fin, Wp, bp, out);
}

// Round 5
// 9821.552 us; speedup vs baseline: 1.2808x; 1.0101x over previous
//
#include <hip/hip_runtime.h>
#include <stdint.h>

// Problem dims
#define BATCH 128
#define SEQ   512
#define DIN   256
#define HID   512
#define NWG_L0 128
#define NWG   256    // 1 WG per CU
#define TPB   256    // 4 waves
#define NSLOT 513
#define OUTD  1275
#define HSLOT (BATCH * HID)
#define GSZ   16     // WGs per barrier group
#define NGRP  16

typedef __attribute__((ext_vector_type(8))) short bf16x8;
typedef __attribute__((ext_vector_type(4))) unsigned short ushort4v;
typedef __attribute__((ext_vector_type(4))) float f32x4;

static __device__ __forceinline__ unsigned short f2bf(float f) {
  unsigned int u = __builtin_bit_cast(unsigned int, f);
  u += 0x7FFFu + ((u >> 16) & 1u);  // RNE
  return (unsigned short)(u >> 16);
}
static __device__ __forceinline__ float sigmoidf_fast(float v) {
  float e = __expf(-fabsf(v));
  float s = 1.0f / (1.0f + e);
  return v >= 0.0f ? s : 1.0f - s;
}
static __device__ __forceinline__ float tanhf_fast(float v) {
  float e = __expf(-2.0f * fabsf(v));
  float t = (1.0f - e) / (1.0f + e);
  return v >= 0.0f ? t : -t;
}

// x -> bf16 MFMA-fragment order: xb[(((p*8+mi)*8+kt)*64+lane)*8]
__global__ __launch_bounds__(256) void xprep(const float* __restrict__ x,
                                             unsigned short* __restrict__ xb) {
  int p = blockIdx.x;
  int lane = threadIdx.x & 63;
  int g4 = threadIdx.x >> 6;
  int c15 = lane & 15, q = lane >> 4;
  for (int g = 0; g < 16; ++g) {
    int idx = g * 4 + g4;  // (mi,kt)
    int mi = idx >> 3, kt = idx & 7;
    int row = mi * 16 + c15;
    const float* src = x + ((size_t)row * SEQ + p) * DIN + kt * 32 + q * 8;
    f32x4 a = *(const f32x4*)src;
    f32x4 b = *(const f32x4*)(src + 4);
    bf16x8 v;
    v[0] = (short)f2bf(a[0]); v[1] = (short)f2bf(a[1]);
    v[2] = (short)f2bf(a[2]); v[3] = (short)f2bf(a[3]);
    v[4] = (short)f2bf(b[0]); v[5] = (short)f2bf(b[1]);
    v[6] = (short)f2bf(b[2]); v[7] = (short)f2bf(b[3]);
    *(bf16x8*)&xb[((((size_t)p * 8 + mi) * 8 + kt) * 64 + lane) * 8] = v;
  }
}

// Persistent 2-layer LSTM. 256 WGs x 256 thr (1/CU). WG owns 4 units of one
// layer (16 gate-cols = one MFMA col-tile). B-fragments live in LDS in exact
// MFMA fragment layout [kt][lane][8]: wave-linear ds_read_b128 (conflict-free),
// identical addresses across the 4 waves, zero VGPR pressure. Cell state in
// VGPRs; gate pairing in-wave (shfl_xor 4/8/12). h exchanged in fragment
// layout via L3-resident scratch (regular stores + agent release/acquire).
// Hierarchical grid barrier: 16 groups x 16 WGs -> root; one per slot.
template <bool USE_XB>
__global__ __launch_bounds__(TPB, 1) void lstm_persistent(
    const float* __restrict__ x, const unsigned short* __restrict__ xb,
    const float* __restrict__ W0, const float* __restrict__ b0,
    const float* __restrict__ W1, const float* __restrict__ b1,
    unsigned int* __restrict__ root_cnt, unsigned int* __restrict__ grp_cnt,
    unsigned short* __restrict__ h0buf, unsigned short* __restrict__ h1buf,
    float* __restrict__ h1fin)
{
  __shared__ unsigned short sWf[32 * 64 * 8];  // 32 KB: B-frags, [kt][lane][8]
  __shared__ unsigned short stage[BATCH * 4];  // 128 rows x 4 units (1 KB)

  const int tid  = threadIdx.x;
  const int wgid = blockIdx.x;
  const bool isA = (wgid < NWG_L0);
  const int unit0 = (isA ? wgid : (wgid - NWG_L0)) << 2;  // 4 units per WG
  const int kt0 = unit0 >> 5;          // fragment coords of this unit block
  const int q0  = (unit0 >> 3) & 3;
  const int j0  = unit0 & 7;           // 0 or 4
  const int lane = tid & 63;
  const int wv   = tid >> 6;           // 0..3: rows [wv*32, wv*32+32)
  const int c15  = lane & 15;          // col: gate = c15>>2, unit = c15&3
  const int q    = lane >> 4;
  const int uu   = c15 & 3;
  const int gate = c15 >> 2;
  const int grp  = wgid >> 4;          // barrier group
  unsigned int* my_grp = grp_cnt + grp * 32;  // 128-B spaced counters

  // ---- one-time: weights -> LDS in MFMA fragment layout (per-lane direct) ----
  {
    const int KT = isA ? 24 : 32;      // K/32
    const float* W = isA ? W0 : W1;
    for (int f = tid; f < KT * 64; f += TPB) {
      int ln = f & 63;
      int kt = f >> 6;
      int qq = ln >> 4, cc = ln & 15;
      int gcol = (cc >> 2) * HID + unit0 + (cc & 3);
      int kbase = kt * 32 + qq * 8;
      bf16x8 v;
#pragma unroll
      for (int j = 0; j < 8; ++j)
        v[j] = (short)f2bf(W[(size_t)(kbase + j) * 2048 + gcol]);
      *(bf16x8*)&sWf[(size_t)f * 8] = v;
    }
  }
  __syncthreads();

  const float* bv = isA ? b0 : b1;
  const float bias = bv[gate * HID + unit0 + uu];

  f32x4 cst[2];  // cell state (c15<4 lanes): rows wv*32+sub*16+q*4+r, unit uu
  cst[0] = (f32x4){0.f, 0.f, 0.f, 0.f};
  cst[1] = (f32x4){0.f, 0.f, 0.f, 0.f};

#define BFRAG(kt) (*(const bf16x8*)&sWf[(((kt) << 6) + lane) << 3])

  for (int p = 0; p < NSLOT; ++p) {
    const unsigned short* h0rd = h0buf + ((p + 1) & 1) * HSLOT;
    unsigned short* h0wr       = h0buf + (p & 1) * HSLOT;
    const unsigned short* h1rd = h1buf + (p & 1) * HSLOT;
    unsigned short* h1wr       = h1buf + ((p + 1) & 1) * HSLOT;
    const bool active = isA ? (p < SEQ) : (p >= 1);

    f32x4 acc[2];
    acc[0] = (f32x4){bias, bias, bias, bias};
    acc[1] = (f32x4){bias, bias, bias, bias};

    // ---- layer0 x-part: no barrier dependency (overlaps the wait) ----
    if (isA && active) {
#pragma unroll
      for (int sub = 0; sub < 2; ++sub) {
        int miG = wv * 2 + sub;
        bf16x8 ax[8];
        if (USE_XB) {
          const unsigned short* xp = xb + ((((size_t)p * 8 + miG) * 8) * 64 + lane) * 8;
#pragma unroll
          for (int kt = 0; kt < 8; ++kt)
            ax[kt] = *(const bf16x8*)(xp + (size_t)kt * 64 * 8);
        } else {
          const float* xp0 = x + (((size_t)(miG * 16 + c15)) * SEQ + p) * DIN + q * 8;
#pragma unroll
          for (int kt = 0; kt < 8; ++kt) {
            f32x4 a = *(const f32x4*)(xp0 + kt * 32);
            f32x4 b = *(const f32x4*)(xp0 + kt * 32 + 4);
            ax[kt][0] = (short)f2bf(a[0]); ax[kt][1] = (short)f2bf(a[1]);
            ax[kt][2] = (short)f2bf(a[2]); ax[kt][3] = (short)f2bf(a[3]);
            ax[kt][4] = (short)f2bf(b[0]); ax[kt][5] = (short)f2bf(b[1]);
            ax[kt][6] = (short)f2bf(b[2]); ax[kt][7] = (short)f2bf(b[3]);
          }
        }
#pragma unroll
        for (int kt = 0; kt < 8; ++kt)
          acc[sub] = __builtin_amdgcn_mfma_f32_16x16x32_bf16(ax[kt], BFRAG(kt), acc[sub], 0, 0, 0);
      }
    }

    // ---- wait: slot p-1 fully published (root == 16*p) ----
    __syncthreads();
    if (tid == 0 && p > 0) {
      unsigned int target = (unsigned int)(GSZ * p);
      while (__hip_atomic_load(root_cnt, __ATOMIC_RELAXED, __HIP_MEMORY_SCOPE_AGENT) < target)
        __builtin_amdgcn_s_sleep(1);
      (void)__hip_atomic_load(root_cnt, __ATOMIC_ACQUIRE, __HIP_MEMORY_SCOPE_AGENT);
    }
    __syncthreads();

    // ---- dependent half ----
    if (active) {
      if (isA) {
#pragma unroll
        for (int sub = 0; sub < 2; ++sub) {
          int miG = wv * 2 + sub;
          const unsigned short* hp = h0rd + ((size_t)miG * 16 * 64) * 8 + (size_t)lane * 8;
          bf16x8 ah[16];
#pragma unroll
          for (int j = 0; j < 16; ++j)
            ah[j] = *(const bf16x8*)(hp + (size_t)j * 64 * 8);
#pragma unroll
          for (int j = 0; j < 16; ++j)
            acc[sub] = __builtin_amdgcn_mfma_f32_16x16x32_bf16(ah[j], BFRAG(8 + j), acc[sub], 0, 0, 0);
        }
      } else {
#pragma unroll
        for (int sub = 0; sub < 2; ++sub) {
          int miG = wv * 2 + sub;
          const unsigned short* hp0 = h0rd + ((size_t)miG * 16 * 64) * 8 + (size_t)lane * 8;
          const unsigned short* hp1 = h1rd + ((size_t)miG * 16 * 64) * 8 + (size_t)lane * 8;
          bf16x8 a0[16];
#pragma unroll
          for (int j = 0; j < 16; ++j)
            a0[j] = *(const bf16x8*)(hp0 + (size_t)j * 64 * 8);
#pragma unroll
          for (int j = 0; j < 16; ++j)
            acc[sub] = __builtin_amdgcn_mfma_f32_16x16x32_bf16(a0[j], BFRAG(j), acc[sub], 0, 0, 0);
          bf16x8 a1[16];
#pragma unroll
          for (int j = 0; j < 16; ++j)
            a1[j] = *(const bf16x8*)(hp1 + (size_t)j * 64 * 8);
#pragma unroll
          for (int j = 0; j < 16; ++j)
            acc[sub] = __builtin_amdgcn_mfma_f32_16x16x32_bf16(a1[j], BFRAG(16 + j), acc[sub], 0, 0, 0);
        }
      }

      // gates: all 4 in-wave (i:c15 0-3, f:4-7, g:8-11, o:12-15)
#pragma unroll
      for (int sub = 0; sub < 2; ++sub)
#pragma unroll
        for (int r = 0; r < 4; ++r) {
          float v = acc[sub][r];
          float vf = __shfl_xor(v, 4);
          float vg = __shfl_xor(v, 8);
          float vo = __shfl_xor(v, 12);
          if (c15 < 4) {
            float cn = sigmoidf_fast(vf) * cst[sub][r] + sigmoidf_fast(v) * tanhf_fast(vg);
            cst[sub][r] = cn;
            float hn = sigmoidf_fast(vo) * tanhf_fast(cn);
            int grow = wv * 32 + sub * 16 + q * 4 + r;
            stage[grow * 4 + uu] = f2bf(hn);
            if (!isA && p == NSLOT - 1)
              h1fin[(size_t)grow * HID + unit0 + uu] = hn;
          }
        }
    }
    __syncthreads();

    // ---- publish 4 units x 128 rows in fragment layout (regular stores) ----
    if (active && tid < 128) {
      int mi = tid >> 4, r15 = tid & 15;
      ushort4v v = *(const ushort4v*)&stage[tid * 4];
      unsigned short* dst = (isA ? h0wr : h1wr) +
          (((size_t)mi * 16 + kt0) * 64 + q0 * 16 + r15) * 8 + j0;
      *(ushort4v*)dst = v;
    }
    __syncthreads();  // drains vmcnt: stores complete before release

    // ---- hierarchical arrive: group counter -> root ----
    if (tid == 0) {
      __hip_atomic_fetch_add(my_grp, 1u, __ATOMIC_RELEASE, __HIP_MEMORY_SCOPE_AGENT);
      if ((wgid & (GSZ - 1)) == 0) {
        unsigned int gt = (unsigned int)(GSZ * (p + 1));
        while (__hip_atomic_load(my_grp, __ATOMIC_RELAXED, __HIP_MEMORY_SCOPE_AGENT) < gt)
          __builtin_amdgcn_s_sleep(1);
        (void)__hip_atomic_load(my_grp, __ATOMIC_ACQUIRE, __HIP_MEMORY_SCOPE_AGENT);
        __hip_atomic_fetch_add(root_cnt, 1u, __ATOMIC_RELEASE, __HIP_MEMORY_SCOPE_AGENT);
      }
    }
  }
#undef BFRAG
}

__global__ __launch_bounds__(256) void proj_kernel(
    const float* __restrict__ h1, const float* __restrict__ Wp,
    const float* __restrict__ bp, float* __restrict__ out)
{
  int o = blockIdx.x * 256 + threadIdx.x;
  int b = blockIdx.y;
  if (o >= OUTD) return;
  const float* hr = h1 + (size_t)b * HID;
  float acc = bp[o];
#pragma unroll 8
  for (int k = 0; k < HID; ++k)
    acc = fmaf(hr[k], Wp[(size_t)k * OUTD + o], acc);
  out[(size_t)b * OUTD + o] = acc;
}

extern "C" void kernel_launch(void* const* d_in, const int* in_sizes, int n_in,
                              void* d_out, int out_size, void* d_ws, size_t ws_size,
                              hipStream_t stream) {
  const float* x  = (const float*)d_in[0];
  const float* W0 = (const float*)d_in[1];
  const float* b0 = (const float*)d_in[2];
  const float* W1 = (const float*)d_in[3];
  const float* b1 = (const float*)d_in[4];
  const float* Wp = (const float*)d_in[5];
  const float* bp = (const float*)d_in[6];
  float* out = (float*)d_out;

  char* ws = (char*)d_ws;
  unsigned int* root  = (unsigned int*)ws;                        // root counter
  unsigned int* grp   = (unsigned int*)(ws + 128);                // 16 x 128 B
  unsigned short* h0b = (unsigned short*)(ws + 4096);             // 256 KB (2 slots)
  unsigned short* h1b = (unsigned short*)(ws + 4096 + 262144);    // 256 KB
  float* h1fin        = (float*)(ws + 4096 + 2 * 262144);         // 256 KB
  unsigned short* xbp = (unsigned short*)(ws + 4096 + 3 * 262144);// 32 MB
  const size_t need_xb = 4096 + 3 * 262144 + (size_t)SEQ * BATCH * DIN * 2;
  const bool use_xb = (ws_size >= need_xb);

  hipMemsetAsync(d_ws, 0, 4096 + 2 * 262144, stream);
  if (use_xb) {
    hipLaunchKernelGGL(xprep, dim3(SEQ), dim3(256), 0, stream, x, xbp);
    hipLaunchKernelGGL(lstm_persistent<true>, dim3(NWG), dim3(TPB), 0, stream,
                       x, xbp, W0, b0, W1, b1, root, grp, h0b, h1b, h1fin);
  } else {
    hipLaunchKernelGGL(lstm_persistent<false>, dim3(NWG), dim3(TPB), 0, stream,
                       x, xbp, W0, b0, W1, b1, root, grp, h0b, h1b, h1fin);
  }
  hipLaunchKernelGGL(proj_kernel, dim3((OUTD + 255) / 256, BATCH), dim3(256), 0, stream,
                     h1fin, Wp, bp, out);
}

// Round 6
// 4211.743 us; speedup vs baseline: 2.9867x; 2.3319x over previous
//
#include <hip/hip_runtime.h>
#include <stdint.h>

// Problem dims
#define BATCH 128
#define SEQ   512
#define DIN   256
#define HID   512
#define NWG_L0 128
#define NWG   256    // 1 WG per CU
#define TPB   256    // 4 waves
#define NSLOT 513
#define OUTD  1275
#define HSLOT (BATCH * HID)
#define GSZ   16     // WGs per barrier group (16 groups)

typedef __attribute__((ext_vector_type(8))) short bf16x8;
typedef __attribute__((ext_vector_type(4))) float f32x4;

static __device__ __forceinline__ unsigned short f2bf(float f) {
  unsigned int u = __builtin_bit_cast(unsigned int, f);
  u += 0x7FFFu + ((u >> 16) & 1u);  // RNE
  return (unsigned short)(u >> 16);
}
static __device__ __forceinline__ float sigmoidf_fast(float v) {
  float e = __expf(-fabsf(v));
  float s = 1.0f / (1.0f + e);
  return v >= 0.0f ? s : 1.0f - s;
}
static __device__ __forceinline__ float tanhf_fast(float v) {
  float e = __expf(-2.0f * fabsf(v));
  float t = (1.0f - e) / (1.0f + e);
  return v >= 0.0f ? t : -t;
}

// Fine-grained (coherence-point) accesses: sc0 sc1 bypass L1+L2 — no cache
// maintenance (wbl2/inv) needed anywhere in the steady-state loop.
static __device__ __forceinline__ void ldg_nc(bf16x8& d, const unsigned short* p) {
  asm volatile("global_load_dwordx4 %0, %1, off sc0 sc1" : "=v"(d) : "v"(p));
}
static __device__ __forceinline__ void stg_nc8(unsigned short* p, unsigned long long v) {
  asm volatile("global_store_dwordx2 %0, %1, off sc0 sc1" :: "v"(p), "v"(v) : "memory");
}
// Wait until <=N vmem outstanding, register-tying 16 fragment results so the
// compiler cannot schedule their consumers before the wait.
#define WAIT_TIE16_N(A, N)                                                    \
  asm volatile("s_waitcnt vmcnt(" #N ")"                                      \
               : "+v"((A)[0]), "+v"((A)[1]), "+v"((A)[2]), "+v"((A)[3]),      \
                 "+v"((A)[4]), "+v"((A)[5]), "+v"((A)[6]), "+v"((A)[7]),      \
                 "+v"((A)[8]), "+v"((A)[9]), "+v"((A)[10]), "+v"((A)[11]),    \
                 "+v"((A)[12]), "+v"((A)[13]), "+v"((A)[14]), "+v"((A)[15])   \
               :: "memory")

// x -> bf16 MFMA-fragment order: xb[(((p*8+mi)*8+kt)*64+lane)*8]
__global__ __launch_bounds__(256) void xprep(const float* __restrict__ x,
                                             unsigned short* __restrict__ xb) {
  int p = blockIdx.x;
  int lane = threadIdx.x & 63;
  int g4 = threadIdx.x >> 6;
  int c15 = lane & 15, q = lane >> 4;
  for (int g = 0; g < 16; ++g) {
    int idx = g * 4 + g4;  // (mi,kt)
    int mi = idx >> 3, kt = idx & 7;
    int row = mi * 16 + c15;
    const float* src = x + ((size_t)row * SEQ + p) * DIN + kt * 32 + q * 8;
    f32x4 a = *(const f32x4*)src;
    f32x4 b = *(const f32x4*)(src + 4);
    bf16x8 v;
    v[0] = (short)f2bf(a[0]); v[1] = (short)f2bf(a[1]);
    v[2] = (short)f2bf(a[2]); v[3] = (short)f2bf(a[3]);
    v[4] = (short)f2bf(b[0]); v[5] = (short)f2bf(b[1]);
    v[6] = (short)f2bf(b[2]); v[7] = (short)f2bf(b[3]);
    *(bf16x8*)&xb[((((size_t)p * 8 + mi) * 8 + kt) * 64 + lane) * 8] = v;
  }
}

// Persistent 2-layer LSTM. 256 WGs x 256 thr (1/CU). WG owns 4 units (16
// gate-cols = one MFMA col-tile); B-frags in LDS fragment layout (conflict-
// free). Cell state in VGPRs; gates paired in-wave (shfl_xor 4/8/12).
// h exchanged via fine-grained sc0sc1 global scratch (no cache ops);
// hierarchical relaxed barrier (16x16 -> root), one per slot.
template <bool USE_XB>
__global__ __launch_bounds__(TPB, 1) void lstm_persistent(
    const float* __restrict__ x, const unsigned short* __restrict__ xb,
    const float* __restrict__ W0, const float* __restrict__ b0,
    const float* __restrict__ W1, const float* __restrict__ b1,
    unsigned int* __restrict__ root_cnt, unsigned int* __restrict__ grp_cnt,
    unsigned short* __restrict__ h0buf, unsigned short* __restrict__ h1buf,
    float* __restrict__ h1fin)
{
  __shared__ unsigned short sWf[32 * 64 * 8];  // 32 KB: B-frags, [kt][lane][8]
  __shared__ unsigned short stage[BATCH * 4];  // 128 rows x 4 units (1 KB)

  const int tid  = threadIdx.x;
  const int wgid = blockIdx.x;
  const bool isA = (wgid < NWG_L0);
  const int unit0 = (isA ? wgid : (wgid - NWG_L0)) << 2;  // 4 units per WG
  const int kt0 = unit0 >> 5;          // fragment coords of this unit block
  const int q0  = (unit0 >> 3) & 3;
  const int j0  = unit0 & 7;           // 0 or 4
  const int lane = tid & 63;
  const int wv   = tid >> 6;           // 0..3: rows [wv*32, wv*32+32)
  const int c15  = lane & 15;          // col: gate = c15>>2, unit = c15&3
  const int q    = lane >> 4;
  const int uu   = c15 & 3;
  const int gate = c15 >> 2;
  const int grp  = wgid >> 4;
  unsigned int* my_grp = grp_cnt + grp * 32;  // 128-B spaced counters

  // ---- one-time: weights -> LDS in MFMA fragment layout ----
  {
    const int KT = isA ? 24 : 32;      // K/32
    const float* W = isA ? W0 : W1;
    for (int f = tid; f < KT * 64; f += TPB) {
      int ln = f & 63;
      int kt = f >> 6;
      int qq = ln >> 4, cc = ln & 15;
      int gcol = (cc >> 2) * HID + unit0 + (cc & 3);
      int kbase = kt * 32 + qq * 8;
      bf16x8 v;
#pragma unroll
      for (int j = 0; j < 8; ++j)
        v[j] = (short)f2bf(W[(size_t)(kbase + j) * 2048 + gcol]);
      *(bf16x8*)&sWf[(size_t)f * 8] = v;
    }
  }
  __syncthreads();

  const float* bv = isA ? b0 : b1;
  const float bias = bv[gate * HID + unit0 + uu];

  f32x4 cst[2];  // cell state (c15<4 lanes): rows wv*32+sub*16+q*4+r, unit uu
  cst[0] = (f32x4){0.f, 0.f, 0.f, 0.f};
  cst[1] = (f32x4){0.f, 0.f, 0.f, 0.f};

#define BFRAG(kt) (*(const bf16x8*)&sWf[(((kt) << 6) + lane) << 3])

  for (int p = 0; p < NSLOT; ++p) {
    const unsigned short* h0rd = h0buf + ((p + 1) & 1) * HSLOT;
    unsigned short* h0wr       = h0buf + (p & 1) * HSLOT;
    const unsigned short* h1rd = h1buf + (p & 1) * HSLOT;
    unsigned short* h1wr       = h1buf + ((p + 1) & 1) * HSLOT;
    const bool active = isA ? (p < SEQ) : (p >= 1);

    f32x4 acc[2];
    acc[0] = (f32x4){bias, bias, bias, bias};
    acc[1] = (f32x4){bias, bias, bias, bias};

    // ---- layer0 x-part: no barrier dependency (overlaps the wait) ----
    if (isA && active) {
#pragma unroll
      for (int sub = 0; sub < 2; ++sub) {
        int miG = wv * 2 + sub;
        bf16x8 ax[8];
        if (USE_XB) {
          const unsigned short* xp = xb + ((((size_t)p * 8 + miG) * 8) * 64 + lane) * 8;
#pragma unroll
          for (int kt = 0; kt < 8; ++kt)
            ax[kt] = *(const bf16x8*)(xp + (size_t)kt * 64 * 8);
        } else {
          const float* xp0 = x + (((size_t)(miG * 16 + c15)) * SEQ + p) * DIN + q * 8;
#pragma unroll
          for (int kt = 0; kt < 8; ++kt) {
            f32x4 a = *(const f32x4*)(xp0 + kt * 32);
            f32x4 b = *(const f32x4*)(xp0 + kt * 32 + 4);
            ax[kt][0] = (short)f2bf(a[0]); ax[kt][1] = (short)f2bf(a[1]);
            ax[kt][2] = (short)f2bf(a[2]); ax[kt][3] = (short)f2bf(a[3]);
            ax[kt][4] = (short)f2bf(b[0]); ax[kt][5] = (short)f2bf(b[1]);
            ax[kt][6] = (short)f2bf(b[2]); ax[kt][7] = (short)f2bf(b[3]);
          }
        }
#pragma unroll
        for (int kt = 0; kt < 8; ++kt)
          acc[sub] = __builtin_amdgcn_mfma_f32_16x16x32_bf16(ax[kt], BFRAG(kt), acc[sub], 0, 0, 0);
      }
    }

    // ---- wait: slot p-1 fully published (root == 16*p), relaxed only ----
    __syncthreads();
    if (tid == 0 && p > 0) {
      unsigned int target = (unsigned int)(GSZ * p);
      while (__hip_atomic_load(root_cnt, __ATOMIC_RELAXED, __HIP_MEMORY_SCOPE_AGENT) < target)
        __builtin_amdgcn_s_sleep(1);
    }
    __syncthreads();

    // ---- dependent half: A-frags via fine-grained loads ----
    if (active) {
      if (isA) {
        const unsigned short* hpA = h0rd + ((size_t)(wv * 2 + 0) * 16 * 64) * 8 + (size_t)lane * 8;
        const unsigned short* hpB = h0rd + ((size_t)(wv * 2 + 1) * 16 * 64) * 8 + (size_t)lane * 8;
        bf16x8 sa[16], sb[16];
#pragma unroll
        for (int j = 0; j < 16; ++j) ldg_nc(sa[j], hpA + (size_t)j * 512);
#pragma unroll
        for (int j = 0; j < 16; ++j) ldg_nc(sb[j], hpB + (size_t)j * 512);
        WAIT_TIE16_N(sa, 16);
#pragma unroll
        for (int j = 0; j < 16; ++j)
          acc[0] = __builtin_amdgcn_mfma_f32_16x16x32_bf16(sa[j], BFRAG(8 + j), acc[0], 0, 0, 0);
        WAIT_TIE16_N(sb, 0);
#pragma unroll
        for (int j = 0; j < 16; ++j)
          acc[1] = __builtin_amdgcn_mfma_f32_16x16x32_bf16(sb[j], BFRAG(8 + j), acc[1], 0, 0, 0);
      } else {
#pragma unroll
        for (int sub = 0; sub < 2; ++sub) {
          int miG = wv * 2 + sub;
          const unsigned short* hp0 = h0rd + ((size_t)miG * 16 * 64) * 8 + (size_t)lane * 8;
          const unsigned short* hp1 = h1rd + ((size_t)miG * 16 * 64) * 8 + (size_t)lane * 8;
          bf16x8 a0[16], a1[16];
#pragma unroll
          for (int j = 0; j < 16; ++j) ldg_nc(a0[j], hp0 + (size_t)j * 512);
#pragma unroll
          for (int j = 0; j < 16; ++j) ldg_nc(a1[j], hp1 + (size_t)j * 512);
          WAIT_TIE16_N(a0, 16);
#pragma unroll
          for (int j = 0; j < 16; ++j)
            acc[sub] = __builtin_amdgcn_mfma_f32_16x16x32_bf16(a0[j], BFRAG(j), acc[sub], 0, 0, 0);
          WAIT_TIE16_N(a1, 0);
#pragma unroll
          for (int j = 0; j < 16; ++j)
            acc[sub] = __builtin_amdgcn_mfma_f32_16x16x32_bf16(a1[j], BFRAG(16 + j), acc[sub], 0, 0, 0);
        }
      }

      // gates: all 4 in-wave (i:c15 0-3, f:4-7, g:8-11, o:12-15)
#pragma unroll
      for (int sub = 0; sub < 2; ++sub)
#pragma unroll
        for (int r = 0; r < 4; ++r) {
          float v = acc[sub][r];
          float vf = __shfl_xor(v, 4);
          float vg = __shfl_xor(v, 8);
          float vo = __shfl_xor(v, 12);
          if (c15 < 4) {
            float cn = sigmoidf_fast(vf) * cst[sub][r] + sigmoidf_fast(v) * tanhf_fast(vg);
            cst[sub][r] = cn;
            float hn = sigmoidf_fast(vo) * tanhf_fast(cn);
            int grow = wv * 32 + sub * 16 + q * 4 + r;
            stage[grow * 4 + uu] = f2bf(hn);
            if (!isA && p == NSLOT - 1)
              h1fin[(size_t)grow * HID + unit0 + uu] = hn;
          }
        }
    }
    __syncthreads();

    // ---- publish in fragment layout (fine-grained stores) ----
    if (active && tid < 128) {
      int mi = tid >> 4, r15 = tid & 15;
      unsigned long long v = *(const unsigned long long*)&stage[tid * 4];
      unsigned short* dst = (isA ? h0wr : h1wr) +
          (((size_t)mi * 16 + kt0) * 64 + q0 * 16 + r15) * 8 + j0;
      stg_nc8(dst, v);
    }
    __syncthreads();  // drains vmcnt: sc0sc1 stores acked at fabric

    // ---- hierarchical arrive (all relaxed; no cache maintenance) ----
    if (tid == 0) {
      __hip_atomic_fetch_add(my_grp, 1u, __ATOMIC_RELAXED, __HIP_MEMORY_SCOPE_AGENT);
      if ((wgid & (GSZ - 1)) == 0) {
        unsigned int gt = (unsigned int)(GSZ * (p + 1));
        while (__hip_atomic_load(my_grp, __ATOMIC_RELAXED, __HIP_MEMORY_SCOPE_AGENT) < gt)
          __builtin_amdgcn_s_sleep(1);
        __hip_atomic_fetch_add(root_cnt, 1u, __ATOMIC_RELAXED, __HIP_MEMORY_SCOPE_AGENT);
      }
    }
  }
#undef BFRAG
}

__global__ __launch_bounds__(256) void proj_kernel(
    const float* __restrict__ h1, const float* __restrict__ Wp,
    const float* __restrict__ bp, float* __restrict__ out)
{
  int o = blockIdx.x * 256 + threadIdx.x;
  int b = blockIdx.y;
  if (o >= OUTD) return;
  const float* hr = h1 + (size_t)b * HID;
  float acc = bp[o];
#pragma unroll 8
  for (int k = 0; k < HID; ++k)
    acc = fmaf(hr[k], Wp[(size_t)k * OUTD + o], acc);
  out[(size_t)b * OUTD + o] = acc;
}

extern "C" void kernel_launch(void* const* d_in, const int* in_sizes, int n_in,
                              void* d_out, int out_size, void* d_ws, size_t ws_size,
                              hipStream_t stream) {
  const float* x  = (const float*)d_in[0];
  const float* W0 = (const float*)d_in[1];
  const float* b0 = (const float*)d_in[2];
  const float* W1 = (const float*)d_in[3];
  const float* b1 = (const float*)d_in[4];
  const float* Wp = (const float*)d_in[5];
  const float* bp = (const float*)d_in[6];
  float* out = (float*)d_out;

  char* ws = (char*)d_ws;
  unsigned int* root  = (unsigned int*)ws;                        // root counter
  unsigned int* grp   = (unsigned int*)(ws + 128);                // 16 x 128 B
  unsigned short* h0b = (unsigned short*)(ws + 4096);             // 256 KB (2 slots)
  unsigned short* h1b = (unsigned short*)(ws + 4096 + 262144);    // 256 KB
  float* h1fin        = (float*)(ws + 4096 + 2 * 262144);         // 256 KB
  unsigned short* xbp = (unsigned short*)(ws + 4096 + 3 * 262144);// 32 MB
  const size_t need_xb = 4096 + 3 * 262144 + (size_t)SEQ * BATCH * DIN * 2;
  const bool use_xb = (ws_size >= need_xb);

  hipMemsetAsync(d_ws, 0, 4096 + 2 * 262144, stream);
  if (use_xb) {
    hipLaunchKernelGGL(xprep, dim3(SEQ), dim3(256), 0, stream, x, xbp);
    hipLaunchKernelGGL(lstm_persistent<true>, dim3(NWG), dim3(TPB), 0, stream,
                       x, xbp, W0, b0, W1, b1, root, grp, h0b, h1b, h1fin);
  } else {
    hipLaunchKernelGGL(lstm_persistent<false>, dim3(NWG), dim3(TPB), 0, stream,
                       x, xbp, W0, b0, W1, b1, root, grp, h0b, h1b, h1fin);
  }
  hipLaunchKernelGGL(proj_kernel, dim3((OUTD + 255) / 256, BATCH), dim3(256), 0, stream,
                     h1fin, Wp, bp, out);
}

// Round 7
// 2629.928 us; speedup vs baseline: 4.7831x; 1.6015x over previous
//
#include <hip/hip_runtime.h>
#include <stdint.h>

// Problem dims
#define BATCH 128
#define SEQ   512
#define DIN   256
#define HID   512
#define NWG   256    // 4 groups x 64 WGs; 1 WG/CU
#define TPB   512    // 8 waves = (m 0..1) x (kq 0..3)
#define NSLOT 513
#define OUTD  1275
#define HSLOT (BATCH * HID)

typedef __attribute__((ext_vector_type(8))) short bf16x8;
typedef __attribute__((ext_vector_type(4))) unsigned int uint4v;
typedef __attribute__((ext_vector_type(4))) float f32x4;

static __device__ __forceinline__ unsigned short f2bf(float f) {
  unsigned int u = __builtin_bit_cast(unsigned int, f);
  u += 0x7FFFu + ((u >> 16) & 1u);  // RNE
  return (unsigned short)(u >> 16);
}
static __device__ __forceinline__ float sigmoidf_fast(float v) {
  float e = __expf(-fabsf(v));
  float s = 1.0f / (1.0f + e);
  return v >= 0.0f ? s : 1.0f - s;
}
static __device__ __forceinline__ float tanhf_fast(float v) {
  float e = __expf(-2.0f * fabsf(v));
  float t = (1.0f - e) / (1.0f + e);
  return v >= 0.0f ? t : -t;
}

// Fine-grained (coherence-point) ops: sc0 sc1 bypass L1+L2 — no cache
// maintenance anywhere in the steady-state loop.
static __device__ __forceinline__ void ldg_nc(bf16x8& d, const unsigned short* p) {
  asm volatile("global_load_dwordx4 %0, %1, off sc0 sc1" : "=v"(d) : "v"(p));
}
static __device__ __forceinline__ void ldg_nc_dw(unsigned int& d, const unsigned int* p) {
  asm volatile("global_load_dword %0, %1, off sc0 sc1" : "=v"(d) : "v"(p));
}
static __device__ __forceinline__ void stg_nc16(unsigned short* p, uint4v v) {
  asm volatile("global_store_dwordx4 %0, %1, off sc0 sc1" :: "v"(p), "v"(v) : "memory");
}
static __device__ __forceinline__ void stg_nc4(unsigned int* p, unsigned int v) {
  asm volatile("global_store_dword %0, %1, off sc0 sc1" :: "v"(p), "v"(v) : "memory");
}
#define WAIT_TIE1(v) asm volatile("s_waitcnt vmcnt(0)" : "+v"(v) :: "memory")
#define WAIT_TIE4(A)                                                          \
  asm volatile("s_waitcnt vmcnt(0)"                                           \
               : "+v"((A)[0]), "+v"((A)[1]), "+v"((A)[2]), "+v"((A)[3])       \
               :: "memory")
#define WAIT_TIE6(A)                                                          \
  asm volatile("s_waitcnt vmcnt(0)"                                           \
               : "+v"((A)[0]), "+v"((A)[1]), "+v"((A)[2]), "+v"((A)[3]),      \
                 "+v"((A)[4]), "+v"((A)[5]) :: "memory")
#define WAIT_TIE8(A)                                                          \
  asm volatile("s_waitcnt vmcnt(0)"                                           \
               : "+v"((A)[0]), "+v"((A)[1]), "+v"((A)[2]), "+v"((A)[3]),      \
                 "+v"((A)[4]), "+v"((A)[5]), "+v"((A)[6]), "+v"((A)[7])       \
               :: "memory")

// x -> bf16 MFMA-fragment order: xb[(((p*8+mi)*8+kt)*64+lane)*8]
__global__ __launch_bounds__(256) void xprep(const float* __restrict__ x,
                                             unsigned short* __restrict__ xb) {
  int p = blockIdx.x;
  int lane = threadIdx.x & 63;
  int g4 = threadIdx.x >> 6;
  int c15 = lane & 15, q = lane >> 4;
  for (int g = 0; g < 16; ++g) {
    int idx = g * 4 + g4;  // (mi,kt)
    int mi = idx >> 3, kt = idx & 7;
    int row = mi * 16 + c15;
    const float* src = x + ((size_t)row * SEQ + p) * DIN + kt * 32 + q * 8;
    f32x4 a = *(const f32x4*)src;
    f32x4 b = *(const f32x4*)(src + 4);
    bf16x8 v;
    v[0] = (short)f2bf(a[0]); v[1] = (short)f2bf(a[1]);
    v[2] = (short)f2bf(a[2]); v[3] = (short)f2bf(a[3]);
    v[4] = (short)f2bf(b[0]); v[5] = (short)f2bf(b[1]);
    v[6] = (short)f2bf(b[2]); v[7] = (short)f2bf(b[3]);
    *(bf16x8*)&xb[((((size_t)p * 8 + mi) * 8 + kt) * 64 + lane) * 8] = v;
  }
}

// Persistent 2-layer LSTM, batch-split. 4 independent groups x 32 batch rows;
// group = 64 WGs (32 L0 + 32 L1), WG owns 16 units (64 gate-cols, col layout
// c = u_local*4 + gate so a unit's 4 gates are adjacent). 8 waves = (M-tile m,
// K-quarter kq): partial-K MFMA into f32 partials, reduced via padded LDS.
// Each WG reads its group's h exactly once per slot (fabric 12 MB/slot total).
// Sync: per-group producer flags (plain sc0sc1 stores), consumers ballot-poll;
// no atomics, no barriers, no cache maintenance, placement-independent.
template <bool USE_XB>
__global__ __launch_bounds__(TPB, 1) void lstm_persistent(
    const float* __restrict__ x, const unsigned short* __restrict__ xb,
    const float* __restrict__ W0, const float* __restrict__ b0,
    const float* __restrict__ W1, const float* __restrict__ b1,
    unsigned int* __restrict__ flags, unsigned short* __restrict__ h0buf,
    unsigned short* __restrict__ h1buf, float* __restrict__ h1fin)
{
  __shared__ unsigned short sWf[4 * 32 * 64 * 8];  // 128 KB B-frags [ct][kt][lane][8]
  __shared__ float red[4 * 32 * 33];               // 16.9 KB padded partials
  __shared__ unsigned short stage[32 * 16];        // 1 KB h stage

  const int tid  = threadIdx.x;
  const int wgid = blockIdx.x;
  const int g    = wgid >> 6;          // group 0..3 (batch rows 32g..32g+31)
  const int r    = wgid & 63;          // role in group
  const bool isA = (r < 32);
  const int unit0 = (isA ? r : r - 32) << 4;  // 16 units per WG
  const int lane = tid & 63;
  const int wv   = tid >> 6;
  const int m    = wv & 1;             // M-tile within group (16 rows)
  const int kq   = wv >> 1;            // K-quarter 0..3
  const int c15  = lane & 15;
  const int q    = lane >> 4;
  const int miG  = g * 2 + m;          // global M-tile
  const int KT   = isA ? 24 : 32;

  // ---- one-time: weights -> LDS fragment layout; col c = u_local*4 + gate ----
  {
    const float* W = isA ? W0 : W1;
    for (int f = tid; f < 4 * KT * 64; f += TPB) {
      int ct = f / (KT * 64);
      int rem = f - ct * (KT * 64);
      int kt = rem >> 6, ln = rem & 63;
      int qq = ln >> 4, cc = ln & 15;
      int u_local = ct * 4 + (cc >> 2);
      int gate = cc & 3;
      int gcol = gate * HID + unit0 + u_local;
      int kbase = kt * 32 + qq * 8;
      bf16x8 v;
#pragma unroll
      for (int j = 0; j < 8; ++j)
        v[j] = (short)f2bf(W[(size_t)(kbase + j) * 2048 + gcol]);
      *(bf16x8*)&sWf[(size_t)f * 8] = v;
    }
  }

  // gate-thread state (tid<256): thread = (row grow_, unit gu) x 2 chunks
  const int grow_ = tid >> 3, gu = tid & 7;
  float bias_c[2][4];
  float cst[2] = {0.f, 0.f};
  if (tid < 256) {
    const float* bv = isA ? b0 : b1;
#pragma unroll
    for (int ch = 0; ch < 2; ++ch)
#pragma unroll
      for (int gt = 0; gt < 4; ++gt)
        bias_c[ch][gt] = bv[gt * HID + unit0 + ch * 8 + gu];
  }
  __syncthreads();

  unsigned int* myflags = flags + g * 64;

#define BFRAG(ct, kt) (*(const bf16x8*)&sWf[((((ct) * KT + (kt)) << 6) + lane) << 3])

  for (int p = 0; p < NSLOT; ++p) {
    const unsigned short* h0rd = h0buf + ((p + 1) & 1) * HSLOT;
    unsigned short* h0wr       = h0buf + (p & 1) * HSLOT;
    const unsigned short* h1rd = h1buf + (p & 1) * HSLOT;
    unsigned short* h1wr       = h1buf + ((p + 1) & 1) * HSLOT;
    const bool active = isA ? (p < SEQ) : (p >= 1);

    f32x4 acc[4];
#pragma unroll
    for (int ct = 0; ct < 4; ++ct) acc[ct] = (f32x4){0.f, 0.f, 0.f, 0.f};

    // ---- pre-poll: L0 x-part (kt<8 of my K-quarter), cached loads ----
    if (isA && active) {
      int ktlo = kq * 6, kthi = ktlo + 6;
      for (int kt = ktlo; kt < kthi && kt < 8; ++kt) {
        bf16x8 ax;
        if (USE_XB) {
          ax = *(const bf16x8*)&xb[((((size_t)p * 8 + miG) * 8 + kt) * 64 + lane) * 8];
        } else {
          const float* xp0 = x + (((size_t)(miG * 16 + c15)) * SEQ + p) * DIN + kt * 32 + q * 8;
          f32x4 a = *(const f32x4*)xp0;
          f32x4 b = *(const f32x4*)(xp0 + 4);
          ax[0] = (short)f2bf(a[0]); ax[1] = (short)f2bf(a[1]);
          ax[2] = (short)f2bf(a[2]); ax[3] = (short)f2bf(a[3]);
          ax[4] = (short)f2bf(b[0]); ax[5] = (short)f2bf(b[1]);
          ax[6] = (short)f2bf(b[2]); ax[7] = (short)f2bf(b[3]);
        }
#pragma unroll
        for (int ct = 0; ct < 4; ++ct)
          acc[ct] = __builtin_amdgcn_mfma_f32_16x16x32_bf16(ax, BFRAG(ct, kt), acc[ct], 0, 0, 0);
      }
    }

    // ---- wait for group slot p-1: ballot-poll 64 producer flags (wave0) ----
    if (wv == 0 && p > 0) {
      const unsigned int* fp = myflags + lane;
      for (;;) {
        unsigned int v;
        ldg_nc_dw(v, fp);
        WAIT_TIE1(v);
        if (__ballot(v >= (unsigned int)p) == ~0ull) break;
        __builtin_amdgcn_s_sleep(1);
      }
    }
    __syncthreads();

    // ---- dependent K-part: fine-grained h loads, partial-K MFMA ----
    if (active) {
      if (isA) {
        if (kq == 1) {         // kt 8..11 -> h0 frag 0..3
          bf16x8 ah[4];
#pragma unroll
          for (int i = 0; i < 4; ++i)
            ldg_nc(ah[i], h0rd + ((size_t)(miG * 16 + i) * 64 + lane) * 8);
          WAIT_TIE4(ah);
#pragma unroll
          for (int i = 0; i < 4; ++i)
#pragma unroll
            for (int ct = 0; ct < 4; ++ct)
              acc[ct] = __builtin_amdgcn_mfma_f32_16x16x32_bf16(ah[i], BFRAG(ct, 8 + i), acc[ct], 0, 0, 0);
        } else if (kq >= 2) {  // kt 12..17 / 18..23 -> h0 frag 4..9 / 10..15
          bf16x8 ah[6];
          int kt0 = kq * 6;
#pragma unroll
          for (int i = 0; i < 6; ++i)
            ldg_nc(ah[i], h0rd + ((size_t)(miG * 16 + (kt0 - 8 + i)) * 64 + lane) * 8);
          WAIT_TIE6(ah);
#pragma unroll
          for (int i = 0; i < 6; ++i)
#pragma unroll
            for (int ct = 0; ct < 4; ++ct)
              acc[ct] = __builtin_amdgcn_mfma_f32_16x16x32_bf16(ah[i], BFRAG(ct, kt0 + i), acc[ct], 0, 0, 0);
        }
      } else {
        bf16x8 ah[8];
        const unsigned short* src = (kq < 2) ? h0rd : h1rd;
        int ktf0 = (kq < 2) ? kq * 8 : (kq - 2) * 8;
#pragma unroll
        for (int i = 0; i < 8; ++i)
          ldg_nc(ah[i], src + ((size_t)(miG * 16 + ktf0 + i) * 64 + lane) * 8);
        WAIT_TIE8(ah);
#pragma unroll
        for (int i = 0; i < 8; ++i)
#pragma unroll
          for (int ct = 0; ct < 4; ++ct)
            acc[ct] = __builtin_amdgcn_mfma_f32_16x16x32_bf16(ah[i], BFRAG(ct, kq * 8 + i), acc[ct], 0, 0, 0);
      }
    }

    // ---- cross-wave K-reduce + gates, 2 chunks of 32 cols (8 units) ----
#pragma unroll
    for (int ch = 0; ch < 2; ++ch) {
      __syncthreads();
      if (active) {
        int lrow = m * 16 + q * 4;
#pragma unroll
        for (int t = 0; t < 2; ++t)
#pragma unroll
          for (int rr = 0; rr < 4; ++rr)
            red[(kq * 32 + lrow + rr) * 33 + t * 16 + c15] = acc[ch * 2 + t][rr];
      }
      __syncthreads();
      if (active && tid < 256) {
        float z[4];
#pragma unroll
        for (int gt = 0; gt < 4; ++gt) {
          float s = bias_c[ch][gt];
          int cidx = gu * 4 + gt;
#pragma unroll
          for (int k2 = 0; k2 < 4; ++k2)
            s += red[(k2 * 32 + grow_) * 33 + cidx];
          z[gt] = s;
        }
        float cn = sigmoidf_fast(z[1]) * cst[ch] + sigmoidf_fast(z[0]) * tanhf_fast(z[2]);
        cst[ch] = cn;
        float hn = sigmoidf_fast(z[3]) * tanhf_fast(cn);
        stage[grow_ * 16 + ch * 8 + gu] = f2bf(hn);
        if (!isA && p == NSLOT - 1)
          h1fin[(size_t)(g * 32 + grow_) * HID + unit0 + ch * 8 + gu] = hn;
      }
    }
    __syncthreads();

    // ---- wave0: publish (frag layout, sc0sc1) + drain + flag; others roll on ----
    if (wv == 0) {
      if (active && tid < 64) {
        int row = tid >> 1, qq2 = tid & 1;
        uint4v v = *(const uint4v*)&stage[row * 16 + qq2 * 8];
        int mi = g * 2 + (row >> 4), r15 = row & 15;
        int ktu = unit0 >> 5;
        int qu = ((unit0 & 31) >> 3) + qq2;
        unsigned short* dst = (isA ? h0wr : h1wr) +
            ((size_t)(mi * 16 + ktu) * 64 + qu * 16 + r15) * 8;
        stg_nc16(dst, v);
      }
      asm volatile("s_waitcnt vmcnt(0)" ::: "memory");  // stores acked at fabric
      if (tid == 0) stg_nc4(myflags + r, (unsigned int)(p + 1));
    }
    // no trailing barrier: next slot's post-poll __syncthreads rejoins waves
  }
#undef BFRAG
}

__global__ __launch_bounds__(256) void proj_kernel(
    const float* __restrict__ h1, const float* __restrict__ Wp,
    const float* __restrict__ bp, float* __restrict__ out)
{
  int o = blockIdx.x * 256 + threadIdx.x;
  int b = blockIdx.y;
  if (o >= OUTD) return;
  const float* hr = h1 + (size_t)b * HID;
  float acc = bp[o];
#pragma unroll 8
  for (int k = 0; k < HID; ++k)
    acc = fmaf(hr[k], Wp[(size_t)k * OUTD + o], acc);
  out[(size_t)b * OUTD + o] = acc;
}

extern "C" void kernel_launch(void* const* d_in, const int* in_sizes, int n_in,
                              void* d_out, int out_size, void* d_ws, size_t ws_size,
                              hipStream_t stream) {
  const float* x  = (const float*)d_in[0];
  const float* W0 = (const float*)d_in[1];
  const float* b0 = (const float*)d_in[2];
  const float* W1 = (const float*)d_in[3];
  const float* b1 = (const float*)d_in[4];
  const float* Wp = (const float*)d_in[5];
  const float* bp = (const float*)d_in[6];
  float* out = (float*)d_out;

  char* ws = (char*)d_ws;
  unsigned int* flags = (unsigned int*)ws;                        // 4 groups x 64 u32 = 1 KB
  unsigned short* h0b = (unsigned short*)(ws + 4096);             // 256 KB (2 slots)
  unsigned short* h1b = (unsigned short*)(ws + 4096 + 262144);    // 256 KB
  float* h1fin        = (float*)(ws + 4096 + 2 * 262144);         // 256 KB
  unsigned short* xbp = (unsigned short*)(ws + 4096 + 3 * 262144);// 32 MB
  const size_t need_xb = 4096 + 3 * 262144 + (size_t)SEQ * BATCH * DIN * 2;
  const bool use_xb = (ws_size >= need_xb);

  hipMemsetAsync(d_ws, 0, 4096 + 2 * 262144, stream);
  if (use_xb) {
    hipLaunchKernelGGL(xprep, dim3(SEQ), dim3(256), 0, stream, x, xbp);
    hipLaunchKernelGGL(lstm_persistent<true>, dim3(NWG), dim3(TPB), 0, stream,
                       x, xbp, W0, b0, W1, b1, flags, h0b, h1b, h1fin);
  } else {
    hipLaunchKernelGGL(lstm_persistent<false>, dim3(NWG), dim3(TPB), 0, stream,
                       x, xbp, W0, b0, W1, b1, flags, h0b, h1b, h1fin);
  }
  hipLaunchKernelGGL(proj_kernel, dim3((OUTD + 255) / 256, BATCH), dim3(256), 0, stream,
                     h1fin, Wp, bp, out);
}